// Round 1
// 846.630 us; speedup vs baseline: 1.1704x; 1.1704x over previous
//
#include <hip/hip_runtime.h>
#include <cstdint>

#define N_NODES 100000
#define NBKT 2048      // dst buckets
#define KNODE 49       // nodes per bucket: ceil(100000/2048)
#define NREG 8         // write regions (~XCDs) per bucket
#define RCAP 320       // capacity per (region,bucket): mean 195, +8.9 sigma
#define SCB 98         // scan blocks: ceil(100000/1024)

// ---------------- pass 1: bucket edges by dst range, fused degree count ----------------
// temp entry: packed (src << 6) | (dst - bucket*KNODE)   [src<2^17, local<49<2^6]
// region = blockIdx.x & 7 -> with round-robin block->XCD dispatch, each
// (region,bucket) write front is single-XCD => full-line combining in that L2.

__global__ void k_bucket(const int* __restrict__ src, const int* __restrict__ dst,
                         int* __restrict__ cnt, int* __restrict__ bcur,
                         int* __restrict__ tmp, int E) {
    int e = blockIdx.x * blockDim.x + threadIdx.x;
    if (e >= E) return;
    int d = dst[e];
    int s = src[e];
    atomicAdd(&cnt[d], 1);
    int b = d / KNODE;
    int cell = ((blockIdx.x & (NREG - 1)) << 11) + b;   // NBKT = 2048 = 1<<11
    int c = atomicAdd(&bcur[cell], 1);
    if (c < RCAP) tmp[(size_t)cell * RCAP + c] = (s << 6) | (d - b * KNODE);
}

// ---------------- hierarchical scan: cnt -> row_start (exclusive), fused dinv ----------------

__global__ void k_scan1(const int* __restrict__ cnt, int* __restrict__ bsum, int n) {
    __shared__ int s[256];
    int t = threadIdx.x;
    int i = blockIdx.x * 1024 + t * 4;
    int v = 0;
    if (i + 3 < n) {
        int4 q = *(const int4*)(cnt + i);
        v = q.x + q.y + q.z + q.w;
    } else {
        for (int j = i; j < n; ++j) v += cnt[j];
    }
    s[t] = v;
    __syncthreads();
    for (int off = 128; off > 0; off >>= 1) {
        if (t < off) s[t] += s[t + off];
        __syncthreads();
    }
    if (t == 0) bsum[blockIdx.x] = s[0];
}

__global__ void k_scan2(const int* __restrict__ bsum, int* __restrict__ boff, int nb) {
    __shared__ int s[128];
    int t = threadIdx.x;
    s[t] = (t < nb) ? bsum[t] : 0;
    __syncthreads();
    for (int off = 1; off < 128; off <<= 1) {
        int v = (t >= off) ? s[t - off] : 0;
        __syncthreads();
        s[t] += v;
        __syncthreads();
    }
    if (t < nb) boff[t] = (t == 0) ? 0 : s[t - 1];
}

__global__ void k_scan3(const int* __restrict__ cnt, const int* __restrict__ boff,
                        int* __restrict__ row_start, float* __restrict__ dinv, int n) {
    __shared__ int s[256];
    int t = threadIdx.x;
    int i = blockIdx.x * 1024 + t * 4;
    int c[4];
    int v = 0;
#pragma unroll
    for (int j = 0; j < 4; ++j) {
        c[j] = (i + j < n) ? cnt[i + j] : 0;
        v += c[j];
    }
    s[t] = v;
    __syncthreads();
    for (int off = 1; off < 256; off <<= 1) {
        int w = (t >= off) ? s[t - off] : 0;
        __syncthreads();
        s[t] += w;
        __syncthreads();
    }
    int base = boff[blockIdx.x] + s[t] - v;   // exclusive prefix for this thread
#pragma unroll
    for (int j = 0; j < 4; ++j) {
        int idx = i + j;
        if (idx < n) {
            row_start[idx] = base;
            dinv[idx] = rsqrtf((float)c[j] + 1.0f);
            base += c[j];
            if (idx == n - 1) row_start[n] = base;
        }
    }
}

// ---------------- pass 2: place edges at final CSR positions ----------------
// one block per bucket: CSR target window ~12.5KB => L2-resident, single XCD.

__global__ void k_bin2(const int* __restrict__ tmp, const int* __restrict__ bcur,
                       const int* __restrict__ row_start, const float* __restrict__ dinv,
                       int2* __restrict__ csr) {
    __shared__ int cur[KNODE];
    int b = blockIdx.x;
    for (int i = threadIdx.x; i < KNODE; i += blockDim.x) cur[i] = 0;
    __syncthreads();
    for (int r = 0; r < NREG; ++r) {
        int cell = (r << 11) + b;
        int nseg = min(bcur[cell], RCAP);
        const int* seg = tmp + (size_t)cell * RCAP;
        for (int i = threadIdx.x; i < nseg; i += blockDim.x) {
            int p = seg[i];
            int li = p & 63;
            int s = p >> 6;
            int d = b * KNODE + li;
            int pos = row_start[d] + atomicAdd(&cur[li], 1);
            csr[pos] = make_int2(s, __float_as_int(dinv[s] * dinv[d]));
        }
    }
}

// ---------------- layer 1 GEMM: x(N,512) @ W1(512,8) ----------------

__global__ void k_gemm1(const float* __restrict__ x, const float* __restrict__ W,
                        float* __restrict__ xw, int n) {
    __shared__ float sW[512 * 8];
    for (int i = threadIdx.x; i < 512 * 8; i += blockDim.x) sW[i] = W[i];
    __syncthreads();
    int r = blockIdx.x * blockDim.x + threadIdx.x;
    if (r >= n) return;
    const float4* xr = (const float4*)(x + (size_t)r * 512);
    float acc[8];
#pragma unroll
    for (int c = 0; c < 8; ++c) acc[c] = 0.f;
    for (int t = 0; t < 128; ++t) {
        float4 v = xr[t];
        const float* sw = &sW[t * 32];
#pragma unroll
        for (int c = 0; c < 8; ++c)
            acc[c] += v.x * sw[c] + v.y * sw[8 + c] + v.z * sw[16 + c] + v.w * sw[24 + c];
    }
    float4* xwo = (float4*)(xw + (size_t)r * 8);
    xwo[0] = make_float4(acc[0], acc[1], acc[2], acc[3]);
    xwo[1] = make_float4(acc[4], acc[5], acc[6], acc[7]);
}

// ---------------- small GEMM with fused bias(+relu) ----------------

template <int FIN, int FOUT, bool RELU>
__global__ void k_gemm_small(const float* __restrict__ h, const float* __restrict__ W,
                             const float* __restrict__ b, float* __restrict__ xw, int n) {
    __shared__ float sW[FIN * FOUT];
    __shared__ float sB[FOUT];
    for (int i = threadIdx.x; i < FIN * FOUT; i += blockDim.x) sW[i] = W[i];
    for (int i = threadIdx.x; i < FOUT; i += blockDim.x) sB[i] = b[i];
    __syncthreads();
    int r = blockIdx.x * blockDim.x + threadIdx.x;
    if (r >= n) return;
    float in[FIN];
    const float4* hp = (const float4*)(h + (size_t)r * FIN);
#pragma unroll
    for (int t = 0; t < FIN / 4; ++t) {
        float4 v = hp[t];
        in[t * 4 + 0] = v.x; in[t * 4 + 1] = v.y; in[t * 4 + 2] = v.z; in[t * 4 + 3] = v.w;
    }
    float4* xwo = (float4*)(xw + (size_t)r * FOUT);
#pragma unroll
    for (int c = 0; c < FOUT; c += 4) {
        float s[4];
#pragma unroll
        for (int j = 0; j < 4; ++j) {
            float a = 0.f;
#pragma unroll
            for (int k = 0; k < FIN; ++k) a += in[k] * sW[k * FOUT + c + j];
            a += sB[c + j];
            if (RELU) a = fmaxf(a, 0.f);
            s[j] = a;
        }
        xwo[c / 4] = make_float4(s[0], s[1], s[2], s[3]);
    }
}

// ---------------- gather-aggregate (fused self-term [+ bias + relu]) ----------------

template <int F, bool FIN_BIAS_RELU>
__global__ void k_gather(const float* __restrict__ xw, const int2* __restrict__ csr,
                         const int* __restrict__ row_start, const float* __restrict__ dinv,
                         const float* __restrict__ b, float* __restrict__ out, int n) {
    int gid = blockIdx.x * blockDim.x + threadIdx.x;
    int node = gid / F;
    int c = gid % F;
    if (node >= n) return;
    float di = dinv[node];
    float acc = xw[(size_t)node * F + c] * di * di;
    int k0 = row_start[node], k1 = row_start[node + 1];
    for (int k = k0; k < k1; ++k) {
        int2 p = csr[k];
        acc += xw[(size_t)p.x * F + c] * __int_as_float(p.y);
    }
    if (FIN_BIAS_RELU) acc = fmaxf(acc + b[c], 0.f);
    out[(size_t)node * F + c] = acc;
}

// ---------------- head prep: fold W3/b3/Wfc into per-node 16-dot ----------------

__global__ void k_prep_head(const float* __restrict__ W3, const float* __restrict__ b3,
                            const float* __restrict__ Wfc, float* __restrict__ v,
                            float* __restrict__ c) {
    int t = threadIdx.x;
    if (t < 32) {
        int j = t & 15;
        const float* wf = Wfc + (t < 16 ? 0 : 32);
        float a = 0.f;
        for (int k = 0; k < 32; ++k) a += W3[j * 32 + k] * wf[k];
        v[t] = a;
    } else if (t < 34) {
        const float* wf = Wfc + (t == 32 ? 0 : 32);
        float a = 0.f;
        for (int k = 0; k < 32; ++k) a += b3[k] * wf[k];
        c[t - 32] = a;
    }
}

__global__ void k_node_head(const float* __restrict__ S3, const float* __restrict__ v,
                            const float* __restrict__ c, float* __restrict__ pi,
                            float* __restrict__ pj, int n) {
    int r = blockIdx.x * blockDim.x + threadIdx.x;
    if (r >= n) return;
    const float4* sp = (const float4*)(S3 + (size_t)r * 16);
    float a = 0.f, bb = 0.f;
#pragma unroll
    for (int t = 0; t < 4; ++t) {
        float4 s = sp[t];
        a += s.x * v[t * 4 + 0] + s.y * v[t * 4 + 1] + s.z * v[t * 4 + 2] + s.w * v[t * 4 + 3];
        bb += s.x * v[16 + t * 4 + 0] + s.y * v[16 + t * 4 + 1] + s.z * v[16 + t * 4 + 2] + s.w * v[16 + t * 4 + 3];
    }
    pi[r] = a + c[0];
    pj[r] = bb + c[1];
}

// ---------------- sample head ----------------

__global__ void k_samples_fast(const int2* __restrict__ samples, const float* __restrict__ pi,
                               const float* __restrict__ pj, const float* __restrict__ bfc,
                               float* __restrict__ out, int S) {
    int i = blockIdx.x * blockDim.x + threadIdx.x;
    if (i >= S) return;
    int2 s = samples[i];
    float z = pi[s.x] + pj[s.y] + bfc[0];
    out[i] = 1.0f / (1.0f + __expf(-z));
}

// ---------------- launch ----------------

extern "C" void kernel_launch(void* const* d_in, const int* in_sizes, int n_in,
                              void* d_out, int out_size, void* d_ws, size_t ws_size,
                              hipStream_t stream) {
    const float* x   = (const float*)d_in[0];
    const int*   ei  = (const int*)d_in[1];
    const int*   smp = (const int*)d_in[2];
    const float* W1  = (const float*)d_in[3];
    const float* b1  = (const float*)d_in[4];
    const float* W2  = (const float*)d_in[5];
    const float* b2  = (const float*)d_in[6];
    const float* W3  = (const float*)d_in[7];
    const float* b3  = (const float*)d_in[8];
    const float* Wfc = (const float*)d_in[9];
    const float* bfc = (const float*)d_in[10];
    float* out = (float*)d_out;

    const int E = in_sizes[1] / 2;
    const int S = in_sizes[2] / 2;
    const int N = N_NODES;
    const int* src = ei;
    const int* dst = ei + E;

    char* w = (char*)d_ws;
    size_t off = 0;
    auto alloc = [&](size_t bytes) {
        char* p = w + off;
        off += (bytes + 255) & ~(size_t)255;
        return p;
    };
    int*   cnt       = (int*)alloc(N * 4);
    int*   row_start = (int*)alloc((N + 1) * 4);
    float* dinv      = (float*)alloc(N * 4);
    int2*  csr       = (int2*)alloc((size_t)E * 8);
    int*   bcur      = (int*)alloc((size_t)NREG * NBKT * 4);
    int*   bsum      = (int*)alloc(128 * 4);
    int*   boff      = (int*)alloc(128 * 4);

    // layer buffers; tmp (pass-1 bucket storage, 20MB) overlays this region —
    // tmp is dead before the first layer kernel runs.
    size_t off_layers = off;
    float* xw1       = (float*)alloc((size_t)N * 8 * 4);
    float* h1        = (float*)alloc((size_t)N * 8 * 4);
    float* S2        = (float*)alloc((size_t)N * 8 * 4);
    float* h2        = (float*)alloc((size_t)N * 16 * 4);
    float* S3        = (float*)alloc((size_t)N * 16 * 4);
    float* vhead     = (float*)alloc(32 * 4);
    float* chead     = (float*)alloc(2 * 4);
    float* pi        = (float*)alloc(N * 4);
    float* pj        = (float*)alloc(N * 4);
    int*   tmp       = (int*)(w + off_layers);
    size_t tmp_end = off_layers + (size_t)NREG * NBKT * RCAP * 4;
    if (tmp_end > off) off = (tmp_end + 255) & ~(size_t)255;

    dim3 B(256);

    hipMemsetAsync(cnt, 0, N * 4, stream);
    hipMemsetAsync(bcur, 0, (size_t)NREG * NBKT * 4, stream);

    // CSR build: bucket-partition (pass 1, fused degree) -> scan (fused dinv) -> place (pass 2)
    k_bucket<<<dim3((E + 255) / 256), B, 0, stream>>>(src, dst, cnt, bcur, tmp, E);
    k_scan1<<<dim3(SCB), B, 0, stream>>>(cnt, bsum, N);
    k_scan2<<<dim3(1), dim3(128), 0, stream>>>(bsum, boff, SCB);
    k_scan3<<<dim3(SCB), B, 0, stream>>>(cnt, boff, row_start, dinv, N);
    k_bin2<<<dim3(NBKT), B, 0, stream>>>(tmp, bcur, row_start, dinv, csr);

    // layer 1: xw1 = x@W1 ; h1 = relu(agg8(xw1) + b1)
    k_gemm1<<<dim3((N + 255) / 256), B, 0, stream>>>(x, W1, xw1, N);
    k_gather<8, true><<<dim3(((size_t)N * 8 + 255) / 256), B, 0, stream>>>(xw1, csr, row_start, dinv, b1, h1, N);

    // layer 2 (linearity): S2 = agg8(h1) ; h2 = relu(S2@W2 + b2)
    k_gather<8, false><<<dim3(((size_t)N * 8 + 255) / 256), B, 0, stream>>>(h1, csr, row_start, dinv, nullptr, S2, N);
    k_gemm_small<8, 16, true><<<dim3((N + 255) / 256), B, 0, stream>>>(S2, W2, b2, h2, N);

    // layer 3 (linearity): S3 = agg16(h2) ; h3 = S3@W3 + b3 folded into head
    k_gather<16, false><<<dim3(((size_t)N * 16 + 255) / 256), B, 0, stream>>>(h2, csr, row_start, dinv, nullptr, S3, N);

    // head: pi/pj per node, then per-sample sigmoid
    k_prep_head<<<dim3(1), dim3(64), 0, stream>>>(W3, b3, Wfc, vhead, chead);
    k_node_head<<<dim3((N + 255) / 256), B, 0, stream>>>(S3, vhead, chead, pi, pj, N);
    k_samples_fast<<<dim3((S + 255) / 256), B, 0, stream>>>((const int2*)smp, pi, pj, bfc, out, S);
}

// Round 2
// 639.326 us; speedup vs baseline: 1.5499x; 1.3243x over previous
//
#include <hip/hip_runtime.h>
#include <cstdint>

#define N_NODES 100000
#define NBKT 2048      // dst buckets (1<<11)
#define KNODE 49       // nodes per bucket: ceil(100000/2048)
#define NBLK 256       // partition blocks (1/CU)
#define TPB_P 512      // threads for hist/place

// ---------------- pass A: per-block LDS histogram over dst buckets ----------------

__global__ void k_hist(const int* __restrict__ dst, int* __restrict__ hist, int E) {
    __shared__ int h[NBKT];
    for (int i = threadIdx.x; i < NBKT; i += blockDim.x) h[i] = 0;
    __syncthreads();
    int chunk = (E + NBLK - 1) / NBLK;
    int lo = blockIdx.x * chunk, hi = min(lo + chunk, E);
    for (int i = lo + threadIdx.x; i < hi; i += blockDim.x)
        atomicAdd(&h[dst[i] / KNODE], 1);
    __syncthreads();
    int* hr = hist + (size_t)blockIdx.x * NBKT;
    for (int i = threadIdx.x; i < NBKT; i += blockDim.x) hr[i] = h[i];
}

// ---------------- column prefix over blocks (XCD-grouped order) + bucket totals ----------------
// iterate blocks so same-XCD blocks (r%8 equal) get ADJACENT output segments:
// their partial cache lines then live in ONE L2 -> full write combining.

__global__ void k_offs(const int* __restrict__ hist, int* __restrict__ offs,
                       int* __restrict__ btot) {
    int bkt = blockIdx.x * blockDim.x + threadIdx.x;
    if (bkt >= NBKT) return;
    int run = 0;
    for (int rr = 0; rr < NBLK; ++rr) {
        int r = ((rr & 31) << 3) | (rr >> 5);   // r = k*8 + xcd
        int v = hist[(size_t)r * NBKT + bkt];
        offs[(size_t)r * NBKT + bkt] = run;
        run += v;
    }
    btot[bkt] = run;
}

// single-block exclusive scan of 2048 bucket totals -> bbase[0..NBKT]

__global__ void k_bktscan(const int* __restrict__ btot, int* __restrict__ bbase) {
    __shared__ int s[256];
    int t = threadIdx.x;
    int loc[8];
    int sum = 0;
#pragma unroll
    for (int j = 0; j < 8; ++j) { loc[j] = btot[t * 8 + j]; sum += loc[j]; }
    s[t] = sum;
    __syncthreads();
    for (int off = 1; off < 256; off <<= 1) {
        int v = (t >= off) ? s[t - off] : 0;
        __syncthreads();
        s[t] += v;
        __syncthreads();
    }
    int base = s[t] - sum;   // exclusive prefix for this thread's 8 buckets
#pragma unroll
    for (int j = 0; j < 8; ++j) { bbase[t * 8 + j] = base; base += loc[j]; }
    if (t == 255) bbase[NBKT] = base;
}

// ---------------- pass B: place packed edges at deterministic offsets (LDS cursors) ----------------
// tmp entry: (src << 6) | (dst - bucket*KNODE)   [src < 2^17, local < 49 < 2^6]

__global__ void k_place(const int* __restrict__ src, const int* __restrict__ dst,
                        const int* __restrict__ offs, const int* __restrict__ bbase,
                        int* __restrict__ tmp, int E) {
    __shared__ int cur[NBKT];
    const int* orow = offs + (size_t)blockIdx.x * NBKT;
    for (int i = threadIdx.x; i < NBKT; i += blockDim.x) cur[i] = bbase[i] + orow[i];
    __syncthreads();
    int chunk = (E + NBLK - 1) / NBLK;
    int lo = blockIdx.x * chunk, hi = min(lo + chunk, E);
    for (int i = lo + threadIdx.x; i < hi; i += blockDim.x) {
        int d = dst[i], s = src[i];
        int b = d / KNODE;
        int p = atomicAdd(&cur[b], 1);       // LDS atomic
        tmp[p] = (s << 6) | (d - b * KNODE);
    }
}

// ---------------- per-bucket count + local prefix -> row_start, dinv ----------------
// bucket-major layout == node-id order, so row_start[node] = bbase[b] + local_prefix.

__global__ void k_countscan(const int* __restrict__ tmp, const int* __restrict__ bbase,
                            int* __restrict__ row_start, float* __restrict__ dinv, int n) {
    __shared__ int c[KNODE];
    __shared__ int p[KNODE];
    int b = blockIdx.x;
    int t = threadIdx.x;
    for (int i = t; i < KNODE; i += blockDim.x) c[i] = 0;
    __syncthreads();
    int n0 = bbase[b], n1 = bbase[b + 1];
    for (int i = n0 + t; i < n1; i += blockDim.x)
        atomicAdd(&c[tmp[i] & 63], 1);
    __syncthreads();
    if (t == 0) {
        int run = 0;
        for (int j = 0; j < KNODE; ++j) { p[j] = run; run += c[j]; }
    }
    __syncthreads();
    if (t < KNODE) {
        int node = b * KNODE + t;
        if (node < n) {
            row_start[node] = n0 + p[t];
            dinv[node] = rsqrtf((float)c[t] + 1.0f);
        }
    }
    if (b == 0 && t == 0) row_start[n] = bbase[NBKT];
}

// ---------------- per-bucket final CSR placement ----------------
// csr window per bucket ~12.5KB, single block -> single L2 -> writes combine.

__global__ void k_bin2(const int* __restrict__ tmp, const int* __restrict__ bbase,
                       const int* __restrict__ row_start, const float* __restrict__ dinv,
                       int2* __restrict__ csr, int n) {
    __shared__ int cur[KNODE];
    __shared__ float dd[KNODE];
    int b = blockIdx.x;
    int t = threadIdx.x;
    if (t < KNODE) {
        int node = b * KNODE + t;
        cur[t] = (node < n) ? row_start[node] : 0;
        dd[t] = (node < n) ? dinv[node] : 0.f;
    }
    __syncthreads();
    int n0 = bbase[b], n1 = bbase[b + 1];
    for (int i = n0 + t; i < n1; i += blockDim.x) {
        int e = tmp[i];
        int li = e & 63;
        int s = e >> 6;
        int pos = atomicAdd(&cur[li], 1);    // LDS atomic
        csr[pos] = make_int2(s, __float_as_int(dinv[s] * dd[li]));
    }
}

// ---------------- layer 1 GEMM: x(N,512) @ W1(512,8) ----------------

__global__ void k_gemm1(const float* __restrict__ x, const float* __restrict__ W,
                        float* __restrict__ xw, int n) {
    __shared__ float sW[512 * 8];
    for (int i = threadIdx.x; i < 512 * 8; i += blockDim.x) sW[i] = W[i];
    __syncthreads();
    int r = blockIdx.x * blockDim.x + threadIdx.x;
    if (r >= n) return;
    const float4* xr = (const float4*)(x + (size_t)r * 512);
    float acc[8];
#pragma unroll
    for (int c = 0; c < 8; ++c) acc[c] = 0.f;
    for (int t = 0; t < 128; ++t) {
        float4 v = xr[t];
        const float* sw = &sW[t * 32];
#pragma unroll
        for (int c = 0; c < 8; ++c)
            acc[c] += v.x * sw[c] + v.y * sw[8 + c] + v.z * sw[16 + c] + v.w * sw[24 + c];
    }
    float4* xwo = (float4*)(xw + (size_t)r * 8);
    xwo[0] = make_float4(acc[0], acc[1], acc[2], acc[3]);
    xwo[1] = make_float4(acc[4], acc[5], acc[6], acc[7]);
}

// ---------------- small GEMM with fused bias(+relu) ----------------

template <int FIN, int FOUT, bool RELU>
__global__ void k_gemm_small(const float* __restrict__ h, const float* __restrict__ W,
                             const float* __restrict__ b, float* __restrict__ xw, int n) {
    __shared__ float sW[FIN * FOUT];
    __shared__ float sB[FOUT];
    for (int i = threadIdx.x; i < FIN * FOUT; i += blockDim.x) sW[i] = W[i];
    for (int i = threadIdx.x; i < FOUT; i += blockDim.x) sB[i] = b[i];
    __syncthreads();
    int r = blockIdx.x * blockDim.x + threadIdx.x;
    if (r >= n) return;
    float in[FIN];
    const float4* hp = (const float4*)(h + (size_t)r * FIN);
#pragma unroll
    for (int t = 0; t < FIN / 4; ++t) {
        float4 v = hp[t];
        in[t * 4 + 0] = v.x; in[t * 4 + 1] = v.y; in[t * 4 + 2] = v.z; in[t * 4 + 3] = v.w;
    }
    float4* xwo = (float4*)(xw + (size_t)r * FOUT);
#pragma unroll
    for (int c = 0; c < FOUT; c += 4) {
        float s[4];
#pragma unroll
        for (int j = 0; j < 4; ++j) {
            float a = 0.f;
#pragma unroll
            for (int k = 0; k < FIN; ++k) a += in[k] * sW[k * FOUT + c + j];
            a += sB[c + j];
            if (RELU) a = fmaxf(a, 0.f);
            s[j] = a;
        }
        xwo[c / 4] = make_float4(s[0], s[1], s[2], s[3]);
    }
}

// ---------------- gather-aggregate (fused self-term [+ bias + relu]) ----------------

template <int F, bool FIN_BIAS_RELU>
__global__ void k_gather(const float* __restrict__ xw, const int2* __restrict__ csr,
                         const int* __restrict__ row_start, const float* __restrict__ dinv,
                         const float* __restrict__ b, float* __restrict__ out, int n) {
    int gid = blockIdx.x * blockDim.x + threadIdx.x;
    int node = gid / F;
    int c = gid % F;
    if (node >= n) return;
    float di = dinv[node];
    float acc = xw[(size_t)node * F + c] * di * di;
    int k0 = row_start[node], k1 = row_start[node + 1];
    for (int k = k0; k < k1; ++k) {
        int2 p = csr[k];
        acc += xw[(size_t)p.x * F + c] * __int_as_float(p.y);
    }
    if (FIN_BIAS_RELU) acc = fmaxf(acc + b[c], 0.f);
    out[(size_t)node * F + c] = acc;
}

// ---------------- head prep: fold W3/b3/Wfc into per-node 16-dot ----------------

__global__ void k_prep_head(const float* __restrict__ W3, const float* __restrict__ b3,
                            const float* __restrict__ Wfc, float* __restrict__ v,
                            float* __restrict__ c) {
    int t = threadIdx.x;
    if (t < 32) {
        int j = t & 15;
        const float* wf = Wfc + (t < 16 ? 0 : 32);
        float a = 0.f;
        for (int k = 0; k < 32; ++k) a += W3[j * 32 + k] * wf[k];
        v[t] = a;
    } else if (t < 34) {
        const float* wf = Wfc + (t == 32 ? 0 : 32);
        float a = 0.f;
        for (int k = 0; k < 32; ++k) a += b3[k] * wf[k];
        c[t - 32] = a;
    }
}

__global__ void k_node_head(const float* __restrict__ S3, const float* __restrict__ v,
                            const float* __restrict__ c, float* __restrict__ pi,
                            float* __restrict__ pj, int n) {
    int r = blockIdx.x * blockDim.x + threadIdx.x;
    if (r >= n) return;
    const float4* sp = (const float4*)(S3 + (size_t)r * 16);
    float a = 0.f, bb = 0.f;
#pragma unroll
    for (int t = 0; t < 4; ++t) {
        float4 s = sp[t];
        a += s.x * v[t * 4 + 0] + s.y * v[t * 4 + 1] + s.z * v[t * 4 + 2] + s.w * v[t * 4 + 3];
        bb += s.x * v[16 + t * 4 + 0] + s.y * v[16 + t * 4 + 1] + s.z * v[16 + t * 4 + 2] + s.w * v[16 + t * 4 + 3];
    }
    pi[r] = a + c[0];
    pj[r] = bb + c[1];
}

// ---------------- sample head ----------------

__global__ void k_samples_fast(const int2* __restrict__ samples, const float* __restrict__ pi,
                               const float* __restrict__ pj, const float* __restrict__ bfc,
                               float* __restrict__ out, int S) {
    int i = blockIdx.x * blockDim.x + threadIdx.x;
    if (i >= S) return;
    int2 s = samples[i];
    float z = pi[s.x] + pj[s.y] + bfc[0];
    out[i] = 1.0f / (1.0f + __expf(-z));
}

// ---------------- launch ----------------

extern "C" void kernel_launch(void* const* d_in, const int* in_sizes, int n_in,
                              void* d_out, int out_size, void* d_ws, size_t ws_size,
                              hipStream_t stream) {
    const float* x   = (const float*)d_in[0];
    const int*   ei  = (const int*)d_in[1];
    const int*   smp = (const int*)d_in[2];
    const float* W1  = (const float*)d_in[3];
    const float* b1  = (const float*)d_in[4];
    const float* W2  = (const float*)d_in[5];
    const float* b2  = (const float*)d_in[6];
    const float* W3  = (const float*)d_in[7];
    const float* b3  = (const float*)d_in[8];
    const float* Wfc = (const float*)d_in[9];
    const float* bfc = (const float*)d_in[10];
    float* out = (float*)d_out;

    const int E = in_sizes[1] / 2;
    const int S = in_sizes[2] / 2;
    const int N = N_NODES;
    const int* src = ei;
    const int* dst = ei + E;

    char* w = (char*)d_ws;
    size_t off = 0;
    auto alloc = [&](size_t bytes) {
        char* p = w + off;
        off += (bytes + 255) & ~(size_t)255;
        return p;
    };
    int*   row_start = (int*)alloc((N + 1) * 4);
    float* dinv      = (float*)alloc(N * 4);
    int2*  csr       = (int2*)alloc((size_t)E * 8);
    int*   btot      = (int*)alloc(NBKT * 4);
    int*   bbase     = (int*)alloc((NBKT + 1) * 4);

    // layer buffers; tmp/hist/offs (partition scratch, ~17MB) overlay this
    // region — all dead before the first layer kernel runs.
    size_t off_layers = off;
    float* xw1       = (float*)alloc((size_t)N * 8 * 4);
    float* h1        = (float*)alloc((size_t)N * 8 * 4);
    float* S2        = (float*)alloc((size_t)N * 8 * 4);
    float* h2        = (float*)alloc((size_t)N * 16 * 4);
    float* S3        = (float*)alloc((size_t)N * 16 * 4);
    float* vhead     = (float*)alloc(32 * 4);
    float* chead     = (float*)alloc(2 * 4);
    float* pi        = (float*)alloc(N * 4);
    float* pj        = (float*)alloc(N * 4);

    size_t tmp_off  = off_layers;
    size_t hist_off = tmp_off + (((size_t)E * 4 + 255) & ~(size_t)255);
    size_t offs_off = hist_off + (((size_t)NBLK * NBKT * 4 + 255) & ~(size_t)255);
    int* tmp  = (int*)(w + tmp_off);
    int* hist = (int*)(w + hist_off);
    int* offs = (int*)(w + offs_off);
    size_t scratch_end = offs_off + (size_t)NBLK * NBKT * 4;
    if (scratch_end > off) off = (scratch_end + 255) & ~(size_t)255;

    dim3 B(256);

    // CSR build: zero global atomics, zero memsets.
    k_hist<<<dim3(NBLK), dim3(TPB_P), 0, stream>>>(dst, hist, E);
    k_offs<<<dim3((NBKT + 255) / 256), B, 0, stream>>>(hist, offs, btot);
    k_bktscan<<<dim3(1), B, 0, stream>>>(btot, bbase);
    k_place<<<dim3(NBLK), dim3(TPB_P), 0, stream>>>(src, dst, offs, bbase, tmp, E);
    k_countscan<<<dim3(NBKT), B, 0, stream>>>(tmp, bbase, row_start, dinv, N);
    k_bin2<<<dim3(NBKT), B, 0, stream>>>(tmp, bbase, row_start, dinv, csr, N);

    // layer 1: xw1 = x@W1 ; h1 = relu(agg8(xw1) + b1)
    k_gemm1<<<dim3((N + 255) / 256), B, 0, stream>>>(x, W1, xw1, N);
    k_gather<8, true><<<dim3(((size_t)N * 8 + 255) / 256), B, 0, stream>>>(xw1, csr, row_start, dinv, b1, h1, N);

    // layer 2 (linearity): S2 = agg8(h1) ; h2 = relu(S2@W2 + b2)
    k_gather<8, false><<<dim3(((size_t)N * 8 + 255) / 256), B, 0, stream>>>(h1, csr, row_start, dinv, nullptr, S2, N);
    k_gemm_small<8, 16, true><<<dim3((N + 255) / 256), B, 0, stream>>>(S2, W2, b2, h2, N);

    // layer 3 (linearity): S3 = agg16(h2) ; h3 = S3@W3 + b3 folded into head
    k_gather<16, false><<<dim3(((size_t)N * 16 + 255) / 256), B, 0, stream>>>(h2, csr, row_start, dinv, nullptr, S3, N);

    // head: pi/pj per node, then per-sample sigmoid
    k_prep_head<<<dim3(1), dim3(64), 0, stream>>>(W3, b3, Wfc, vhead, chead);
    k_node_head<<<dim3((N + 255) / 256), B, 0, stream>>>(S3, vhead, chead, pi, pj, N);
    k_samples_fast<<<dim3((S + 255) / 256), B, 0, stream>>>((const int2*)smp, pi, pj, bfc, out, S);
}

// Round 5
// 638.435 us; speedup vs baseline: 1.5521x; 1.0014x over previous
//
#include <hip/hip_runtime.h>
#include <cstdint>

#define N_NODES 100000
#define NBKT 2048      // dst buckets (1<<11)
#define KNODE 49       // nodes per bucket: ceil(100000/2048)
#define NBLK 256       // partition blocks (1/CU)
#define TPB_P 512      // threads for hist/place

// ---------------- pass A: per-block LDS histogram over dst buckets ----------------

__global__ void k_hist(const int* __restrict__ dst, int* __restrict__ hist, int E) {
    __shared__ int h[NBKT];
    for (int i = threadIdx.x; i < NBKT; i += blockDim.x) h[i] = 0;
    __syncthreads();
    int chunk = (E + NBLK - 1) / NBLK;
    int lo = blockIdx.x * chunk, hi = min(lo + chunk, E);
    for (int i = lo + threadIdx.x; i < hi; i += blockDim.x)
        atomicAdd(&h[dst[i] / KNODE], 1);
    __syncthreads();
    int* hr = hist + (size_t)blockIdx.x * NBKT;
    for (int i = threadIdx.x; i < NBKT; i += blockDim.x) hr[i] = h[i];
}

// ---------------- column prefix over blocks (XCD-grouped order) + bucket totals ----------------

__global__ void k_offs(const int* __restrict__ hist, int* __restrict__ offs,
                       int* __restrict__ btot) {
    int bkt = blockIdx.x * blockDim.x + threadIdx.x;
    if (bkt >= NBKT) return;
    int run = 0;
    for (int rr = 0; rr < NBLK; ++rr) {
        int r = ((rr & 31) << 3) | (rr >> 5);   // r = k*8 + xcd
        int v = hist[(size_t)r * NBKT + bkt];
        offs[(size_t)r * NBKT + bkt] = run;
        run += v;
    }
    btot[bkt] = run;
}

// single-block exclusive scan of 2048 bucket totals -> bbase[0..NBKT]

__global__ void k_bktscan(const int* __restrict__ btot, int* __restrict__ bbase) {
    __shared__ int s[256];
    int t = threadIdx.x;
    int loc[8];
    int sum = 0;
#pragma unroll
    for (int j = 0; j < 8; ++j) { loc[j] = btot[t * 8 + j]; sum += loc[j]; }
    s[t] = sum;
    __syncthreads();
    for (int off = 1; off < 256; off <<= 1) {
        int v = (t >= off) ? s[t - off] : 0;
        __syncthreads();
        s[t] += v;
        __syncthreads();
    }
    int base = s[t] - sum;
#pragma unroll
    for (int j = 0; j < 8; ++j) { bbase[t * 8 + j] = base; base += loc[j]; }
    if (t == 255) bbase[NBKT] = base;
}

// ---------------- pass B: place packed edges at deterministic offsets (LDS cursors) ----------------
// tmp entry: (src << 6) | (dst - bucket*KNODE)

__global__ void k_place(const int* __restrict__ src, const int* __restrict__ dst,
                        const int* __restrict__ offs, const int* __restrict__ bbase,
                        int* __restrict__ tmp, int E) {
    __shared__ int cur[NBKT];
    const int* orow = offs + (size_t)blockIdx.x * NBKT;
    for (int i = threadIdx.x; i < NBKT; i += blockDim.x) cur[i] = bbase[i] + orow[i];
    __syncthreads();
    int chunk = (E + NBLK - 1) / NBLK;
    int lo = blockIdx.x * chunk, hi = min(lo + chunk, E);
    for (int i = lo + threadIdx.x; i < hi; i += blockDim.x) {
        int d = dst[i], s = src[i];
        int b = d / KNODE;
        int p = atomicAdd(&cur[b], 1);       // LDS atomic
        tmp[p] = (s << 6) | (d - b * KNODE);
    }
}

// ---------------- per-bucket count + local prefix -> row_start, dinv ----------------

__global__ void k_countscan(const int* __restrict__ tmp, const int* __restrict__ bbase,
                            int* __restrict__ row_start, float* __restrict__ dinv, int n) {
    __shared__ int c[KNODE];
    __shared__ int p[KNODE];
    int b = blockIdx.x;
    int t = threadIdx.x;
    for (int i = t; i < KNODE; i += blockDim.x) c[i] = 0;
    __syncthreads();
    int n0 = bbase[b], n1 = bbase[b + 1];
    for (int i = n0 + t; i < n1; i += blockDim.x)
        atomicAdd(&c[tmp[i] & 63], 1);
    __syncthreads();
    if (t == 0) {
        int run = 0;
        for (int j = 0; j < KNODE; ++j) { p[j] = run; run += c[j]; }
    }
    __syncthreads();
    if (t < KNODE) {
        int node = b * KNODE + t;
        if (node < n) {
            row_start[node] = n0 + p[t];
            dinv[node] = rsqrtf((float)c[t] + 1.0f);
        }
    }
    if (b == 0 && t == 0) row_start[n] = bbase[NBKT];
}

// ---------------- per-bucket final CSR placement ----------------

__global__ void k_bin2(const int* __restrict__ tmp, const int* __restrict__ bbase,
                       const int* __restrict__ row_start, const float* __restrict__ dinv,
                       int2* __restrict__ csr, int n) {
    __shared__ int cur[KNODE];
    __shared__ float dd[KNODE];
    int b = blockIdx.x;
    int t = threadIdx.x;
    if (t < KNODE) {
        int node = b * KNODE + t;
        cur[t] = (node < n) ? row_start[node] : 0;
        dd[t] = (node < n) ? dinv[node] : 0.f;
    }
    __syncthreads();
    int n0 = bbase[b], n1 = bbase[b + 1];
    for (int i = n0 + t; i < n1; i += blockDim.x) {
        int e = tmp[i];
        int li = e & 63;
        int s = e >> 6;
        int pos = atomicAdd(&cur[li], 1);    // LDS atomic
        csr[pos] = make_int2(s, __float_as_int(dinv[s] * dd[li]));
    }
}

// ---------------- layer 1 GEMM: x(N,512) @ W1(512,8), wave-cooperative ----------------
// 8 rows per wave, 8 lanes per row; coalesced 128B row segments per instr.

__global__ void k_gemm1(const float* __restrict__ x, const float* __restrict__ W,
                        float* __restrict__ xw, int n) {
    __shared__ float sWT[8 * 512];
    for (int i = threadIdx.x; i < 4096; i += blockDim.x) {
        int k = i >> 3, c = i & 7;
        sWT[c * 512 + k] = W[i];
    }
    __syncthreads();
    int wid = (blockIdx.x * blockDim.x + threadIdx.x) >> 6;
    int lane = threadIdx.x & 63;
    int r_sub = lane >> 3, j = lane & 7;
    int row = wid * 8 + r_sub;
    if (row >= n) return;
    const float* xr = x + (size_t)row * 512;
    float acc[8];
#pragma unroll
    for (int c = 0; c < 8; ++c) acc[c] = 0.f;
#pragma unroll 4
    for (int it = 0; it < 16; ++it) {
        int kb = it * 32 + j * 4;
        float4 v = *(const float4*)(xr + kb);
#pragma unroll
        for (int c = 0; c < 8; ++c) {
            const float* wt = &sWT[c * 512 + kb];
            acc[c] += v.x * wt[0] + v.y * wt[1] + v.z * wt[2] + v.w * wt[3];
        }
    }
#pragma unroll
    for (int off = 1; off < 8; off <<= 1)
#pragma unroll
        for (int c = 0; c < 8; ++c)
            acc[c] += __shfl_xor(acc[c], off);
    float outv = acc[0];
#pragma unroll
    for (int c = 1; c < 8; ++c) if (j == c) outv = acc[c];
    xw[(size_t)row * 8 + j] = outv;
}

// ---------------- gather 1: h1 = relu(agg8(xw1) + b1), wave-per-node ----------------

__global__ void k_gather1(const float* __restrict__ xw, const int2* __restrict__ csr,
                          const int* __restrict__ row_start, const float* __restrict__ dinv,
                          const float* __restrict__ b, float* __restrict__ out, int n) {
    int wid = (blockIdx.x * blockDim.x + threadIdx.x) >> 6;
    int lane = threadIdx.x & 63;
    if (wid >= n) return;
    int e = lane >> 3, c = lane & 7;
    int k0 = row_start[wid], k1 = row_start[wid + 1];
    float acc = 0.f;
    for (int k = k0 + e; k < k1; k += 8) {
        int2 p = csr[k];
        acc += xw[(size_t)p.x * 8 + c] * __int_as_float(p.y);
    }
    if (e == 0) { float di = dinv[wid]; acc += xw[(size_t)wid * 8 + c] * di * di; }
#pragma unroll
    for (int off = 8; off < 64; off <<= 1) acc += __shfl_xor(acc, off);
    if (lane < 8) out[(size_t)wid * 8 + c] = fmaxf(acc + b[c], 0.f);
}

// ---------------- gather 2 + fused GEMM: h2 = relu(agg8(h1) @ W2 + b2) ----------------

__global__ void k_gather2(const float* __restrict__ h1, const int2* __restrict__ csr,
                          const int* __restrict__ row_start, const float* __restrict__ dinv,
                          const float* __restrict__ W2, const float* __restrict__ b2,
                          float* __restrict__ h2, int n) {
    __shared__ float sW[8 * 16];
    __shared__ float sB[16];
    if (threadIdx.x < 128) sW[threadIdx.x] = W2[threadIdx.x];
    if (threadIdx.x < 16) sB[threadIdx.x] = b2[threadIdx.x];
    __syncthreads();
    int wid = (blockIdx.x * blockDim.x + threadIdx.x) >> 6;
    int lane = threadIdx.x & 63;
    if (wid >= n) return;
    int e = lane >> 3, c = lane & 7;
    int k0 = row_start[wid], k1 = row_start[wid + 1];
    float acc = 0.f;
    for (int k = k0 + e; k < k1; k += 8) {
        int2 p = csr[k];
        acc += h1[(size_t)p.x * 8 + c] * __int_as_float(p.y);
    }
    if (e == 0) { float di = dinv[wid]; acc += h1[(size_t)wid * 8 + c] * di * di; }
#pragma unroll
    for (int off = 8; off < 64; off <<= 1) acc += __shfl_xor(acc, off);
    float s2[8];
#pragma unroll
    for (int k = 0; k < 8; ++k) s2[k] = __shfl(acc, k);
    if (lane < 16) {
        float a = sB[lane];
#pragma unroll
        for (int k = 0; k < 8; ++k) a += s2[k] * sW[k * 16 + lane];
        h2[(size_t)wid * 16 + lane] = fmaxf(a, 0.f);
    }
}

// ---------------- gather 3 + fused head: pi/pj = (agg16(h2)@W3+b3) . Wfc ----------------

__global__ void k_gather3(const float* __restrict__ h2, const int2* __restrict__ csr,
                          const int* __restrict__ row_start, const float* __restrict__ dinv,
                          const float* __restrict__ v, const float* __restrict__ ch,
                          float* __restrict__ pi, float* __restrict__ pj, int n) {
    int wid = (blockIdx.x * blockDim.x + threadIdx.x) >> 6;
    int lane = threadIdx.x & 63;
    if (wid >= n) return;
    int e = lane >> 4, c = lane & 15;
    int k0 = row_start[wid], k1 = row_start[wid + 1];
    float acc = 0.f;
    for (int k = k0 + e; k < k1; k += 4) {
        int2 p = csr[k];
        acc += h2[(size_t)p.x * 16 + c] * __int_as_float(p.y);
    }
    if (e == 0) { float di = dinv[wid]; acc += h2[(size_t)wid * 16 + c] * di * di; }
#pragma unroll
    for (int off = 16; off < 64; off <<= 1) acc += __shfl_xor(acc, off);
    float t = acc * v[c];
    float u = acc * v[16 + c];
#pragma unroll
    for (int off = 1; off < 16; off <<= 1) {
        t += __shfl_xor(t, off);
        u += __shfl_xor(u, off);
    }
    if (lane == 0) { pi[wid] = t + ch[0]; pj[wid] = u + ch[1]; }
}

// ---------------- head prep: fold W3/b3/Wfc into per-node 16-dot ----------------

__global__ void k_prep_head(const float* __restrict__ W3, const float* __restrict__ b3,
                            const float* __restrict__ Wfc, float* __restrict__ v,
                            float* __restrict__ c) {
    int t = threadIdx.x;
    if (t < 32) {
        int j = t & 15;
        const float* wf = Wfc + (t < 16 ? 0 : 32);
        float a = 0.f;
        for (int k = 0; k < 32; ++k) a += W3[j * 32 + k] * wf[k];
        v[t] = a;
    } else if (t < 34) {
        const float* wf = Wfc + (t == 32 ? 0 : 32);
        float a = 0.f;
        for (int k = 0; k < 32; ++k) a += b3[k] * wf[k];
        c[t - 32] = a;
    }
}

// ---------------- sample head ----------------

__global__ void k_samples_fast(const int2* __restrict__ samples, const float* __restrict__ pi,
                               const float* __restrict__ pj, const float* __restrict__ bfc,
                               float* __restrict__ out, int S) {
    int i = blockIdx.x * blockDim.x + threadIdx.x;
    if (i >= S) return;
    int2 s = samples[i];
    float z = pi[s.x] + pj[s.y] + bfc[0];
    out[i] = 1.0f / (1.0f + __expf(-z));
}

// ---------------- launch ----------------

extern "C" void kernel_launch(void* const* d_in, const int* in_sizes, int n_in,
                              void* d_out, int out_size, void* d_ws, size_t ws_size,
                              hipStream_t stream) {
    const float* x   = (const float*)d_in[0];
    const int*   ei  = (const int*)d_in[1];
    const int*   smp = (const int*)d_in[2];
    const float* W1  = (const float*)d_in[3];
    const float* b1  = (const float*)d_in[4];
    const float* W2  = (const float*)d_in[5];
    const float* b2  = (const float*)d_in[6];
    const float* W3  = (const float*)d_in[7];
    const float* b3  = (const float*)d_in[8];
    const float* Wfc = (const float*)d_in[9];
    const float* bfc = (const float*)d_in[10];
    float* out = (float*)d_out;

    const int E = in_sizes[1] / 2;
    const int S = in_sizes[2] / 2;
    const int N = N_NODES;
    const int* src = ei;
    const int* dst = ei + E;

    char* w = (char*)d_ws;
    size_t off = 0;
    auto alloc = [&](size_t bytes) {
        char* p = w + off;
        off += (bytes + 255) & ~(size_t)255;
        return p;
    };
    int*   row_start = (int*)alloc((N + 1) * 4);
    float* dinv      = (float*)alloc(N * 4);
    int2*  csr       = (int2*)alloc((size_t)E * 8);
    int*   btot      = (int*)alloc(NBKT * 4);
    int*   bbase     = (int*)alloc((NBKT + 1) * 4);

    // layer buffers; tmp/hist/offs (partition scratch, ~17MB) overlay this
    // region — all dead before the first layer kernel runs.
    size_t off_layers = off;
    float* xw1       = (float*)alloc((size_t)N * 8 * 4);
    float* h1        = (float*)alloc((size_t)N * 8 * 4);
    float* h2        = (float*)alloc((size_t)N * 16 * 4);
    float* vhead     = (float*)alloc(32 * 4);
    float* chead     = (float*)alloc(2 * 4);
    float* pi        = (float*)alloc(N * 4);
    float* pj        = (float*)alloc(N * 4);

    size_t tmp_off  = off_layers;
    size_t hist_off = tmp_off + (((size_t)E * 4 + 255) & ~(size_t)255);
    size_t offs_off = hist_off + (((size_t)NBLK * NBKT * 4 + 255) & ~(size_t)255);
    int* tmp  = (int*)(w + tmp_off);
    int* hist = (int*)(w + hist_off);
    int* offs = (int*)(w + offs_off);
    size_t scratch_end = offs_off + (size_t)NBLK * NBKT * 4;
    if (scratch_end > off) off = (scratch_end + 255) & ~(size_t)255;

    dim3 B(256);
    const int GN = (N * 64 + 255) / 256;   // wave-per-node grids

    // CSR build: zero global atomics, zero memsets.
    k_hist<<<dim3(NBLK), dim3(TPB_P), 0, stream>>>(dst, hist, E);
    k_offs<<<dim3((NBKT + 255) / 256), B, 0, stream>>>(hist, offs, btot);
    k_bktscan<<<dim3(1), B, 0, stream>>>(btot, bbase);
    k_place<<<dim3(NBLK), dim3(TPB_P), 0, stream>>>(src, dst, offs, bbase, tmp, E);
    k_countscan<<<dim3(NBKT), B, 0, stream>>>(tmp, bbase, row_start, dinv, N);
    k_bin2<<<dim3(NBKT), B, 0, stream>>>(tmp, bbase, row_start, dinv, csr, N);

    // layer 1: xw1 = x@W1 ; h1 = relu(agg8(xw1) + b1)
    k_gemm1<<<dim3(((N + 7) / 8 * 64 + 255) / 256), B, 0, stream>>>(x, W1, xw1, N);
    k_gather1<<<dim3(GN), B, 0, stream>>>(xw1, csr, row_start, dinv, b1, h1, N);

    // layer 2 (linearity): h2 = relu(agg8(h1)@W2 + b2), GEMM fused in-wave
    k_gather2<<<dim3(GN), B, 0, stream>>>(h1, csr, row_start, dinv, W2, b2, h2, N);

    // layer 3 (linearity) + head fold: pi/pj directly from agg16(h2)
    k_prep_head<<<dim3(1), dim3(64), 0, stream>>>(W3, b3, Wfc, vhead, chead);
    k_gather3<<<dim3(GN), B, 0, stream>>>(h2, csr, row_start, dinv, vhead, chead, pi, pj, N);

    // per-sample sigmoid
    k_samples_fast<<<dim3((S + 255) / 256), B, 0, stream>>>((const int2*)smp, pi, pj, bfc, out, S);
}

// Round 6
// 611.947 us; speedup vs baseline: 1.6192x; 1.0433x over previous
//
#include <hip/hip_runtime.h>
#include <cstdint>

#define N_NODES 100000
#define NBKT 2048      // dst buckets (1<<11)
#define KNODE 49       // nodes per bucket: ceil(100000/2048)
#define NBLK 256       // partition blocks
#define TPB_P 512      // threads for hist/place
#define CAP  2048      // LDS staging capacity per bucket in k_finalize (mean 1568, +12 sigma)

// ---------------- pass A: per-block LDS histogram over dst buckets ----------------

__global__ void k_hist(const int* __restrict__ dst, int* __restrict__ hist, int E) {
    __shared__ int h[NBKT];
    for (int i = threadIdx.x; i < NBKT; i += blockDim.x) h[i] = 0;
    __syncthreads();
    int chunk = (E + NBLK - 1) / NBLK;
    int lo = blockIdx.x * chunk, hi = min(lo + chunk, E);
    for (int i = lo + threadIdx.x; i < hi; i += blockDim.x)
        atomicAdd(&h[dst[i] / KNODE], 1);
    __syncthreads();
    int* hr = hist + (size_t)blockIdx.x * NBKT;
    for (int i = threadIdx.x; i < NBKT; i += blockDim.x) hr[i] = h[i];
}

// ---------------- column prefix over blocks, wave-per-bucket (shuffle scan) ----------------
// XCD-grouped block order: same-XCD blocks get adjacent output segments.

__global__ void k_offs(const int* __restrict__ hist, int* __restrict__ offs,
                       int* __restrict__ btot) {
    int bkt = (blockIdx.x * blockDim.x + threadIdx.x) >> 6;
    if (bkt >= NBKT) return;
    int lane = threadIdx.x & 63;
    int vals[4], loc[4];
    int s = 0;
#pragma unroll
    for (int j = 0; j < 4; ++j) {
        int rr = lane * 4 + j;
        int r = ((rr & 31) << 3) | (rr >> 5);   // r = k*8 + xcd
        vals[j] = hist[(size_t)r * NBKT + bkt];
        loc[j] = s;
        s += vals[j];
    }
    int inc = s;
#pragma unroll
    for (int off = 1; off < 64; off <<= 1) {
        int u = __shfl_up(inc, off);
        if (lane >= off) inc += u;
    }
    int excl = inc - s;
#pragma unroll
    for (int j = 0; j < 4; ++j) {
        int rr = lane * 4 + j;
        int r = ((rr & 31) << 3) | (rr >> 5);
        offs[(size_t)r * NBKT + bkt] = excl + loc[j];
    }
    if (lane == 63) btot[bkt] = excl + s;
}

// single-block exclusive scan of 2048 bucket totals -> bbase[0..NBKT]

__global__ void k_bktscan(const int* __restrict__ btot, int* __restrict__ bbase) {
    __shared__ int s[256];
    int t = threadIdx.x;
    int loc[8];
    int sum = 0;
#pragma unroll
    for (int j = 0; j < 8; ++j) { loc[j] = btot[t * 8 + j]; sum += loc[j]; }
    s[t] = sum;
    __syncthreads();
    for (int off = 1; off < 256; off <<= 1) {
        int v = (t >= off) ? s[t - off] : 0;
        __syncthreads();
        s[t] += v;
        __syncthreads();
    }
    int base = s[t] - sum;
#pragma unroll
    for (int j = 0; j < 8; ++j) { bbase[t * 8 + j] = base; base += loc[j]; }
    if (t == 255) bbase[NBKT] = base;
}

// ---------------- pass B: place packed edges at deterministic offsets (LDS cursors) ----------------
// tmp entry: (src << 6) | (dst - bucket*KNODE)

__global__ void k_place(const int* __restrict__ src, const int* __restrict__ dst,
                        const int* __restrict__ offs, const int* __restrict__ bbase,
                        int* __restrict__ tmp, int E) {
    __shared__ int cur[NBKT];
    const int* orow = offs + (size_t)blockIdx.x * NBKT;
    for (int i = threadIdx.x; i < NBKT; i += blockDim.x) cur[i] = bbase[i] + orow[i];
    __syncthreads();
    int chunk = (E + NBLK - 1) / NBLK;
    int lo = blockIdx.x * chunk, hi = min(lo + chunk, E);
    for (int i = lo + threadIdx.x; i < hi; i += blockDim.x) {
        int d = dst[i], s = src[i];
        int b = d / KNODE;
        int p = atomicAdd(&cur[b], 1);       // LDS atomic
        tmp[p] = (s << 6) | (d - b * KNODE);
    }
}

// ---------------- finalize: count + prefix -> row_start/dinv, place csr (src only) ----------------
// one block per bucket; bucket staged in LDS (re-read from global only past CAP).
// csr payload is src alone: dinv[src] is folded into the features, so no
// cross-bucket dinv dependency -> count and place fuse into one kernel.

__global__ void k_finalize(const int* __restrict__ tmp, const int* __restrict__ bbase,
                           int* __restrict__ row_start, float* __restrict__ dinv,
                           int* __restrict__ csr, int n) {
    __shared__ int sE[CAP];
    __shared__ int cnt[KNODE];
    __shared__ int pfx[KNODE];
    __shared__ int cur[KNODE];
    int b = blockIdx.x;
    int t = threadIdx.x;
    for (int i = t; i < KNODE; i += blockDim.x) cnt[i] = 0;
    __syncthreads();
    int n0 = bbase[b], n1 = bbase[b + 1];
    int m = n1 - n0;
    for (int i = t; i < m; i += blockDim.x) {
        int e = tmp[n0 + i];
        if (i < CAP) sE[i] = e;
        atomicAdd(&cnt[e & 63], 1);
    }
    __syncthreads();
    if (t == 0) {
        int run = n0;
        for (int j = 0; j < KNODE; ++j) { pfx[j] = run; run += cnt[j]; }
    }
    __syncthreads();
    if (t < KNODE) {
        int node = b * KNODE + t;
        if (node < n) {
            row_start[node] = pfx[t];
            dinv[node] = rsqrtf((float)cnt[t] + 1.0f);
        }
        cur[t] = pfx[t];
    }
    if (b == 0 && t == 0) row_start[n] = bbase[NBKT];
    __syncthreads();
    for (int i = t; i < m; i += blockDim.x) {
        int e = (i < CAP) ? sE[i] : tmp[n0 + i];
        int pos = atomicAdd(&cur[e & 63], 1);   // LDS atomic
        csr[pos] = e >> 6;
    }
}

// ---------------- layer 1 GEMM: xw1' = (x @ W1) * dinv[row], wave-cooperative ----------------
// 8 rows per wave, 8 lanes per row; coalesced 128B row segments per instr.

__global__ void k_gemm1(const float* __restrict__ x, const float* __restrict__ W,
                        const float* __restrict__ dinv, float* __restrict__ xw, int n) {
    __shared__ float sWT[8 * 512];
    for (int i = threadIdx.x; i < 4096; i += blockDim.x) {
        int k = i >> 3, c = i & 7;
        sWT[c * 512 + k] = W[i];
    }
    __syncthreads();
    int wid = (blockIdx.x * blockDim.x + threadIdx.x) >> 6;
    int lane = threadIdx.x & 63;
    int r_sub = lane >> 3, j = lane & 7;
    int row = wid * 8 + r_sub;
    if (row >= n) return;
    const float* xr = x + (size_t)row * 512;
    float acc[8];
#pragma unroll
    for (int c = 0; c < 8; ++c) acc[c] = 0.f;
#pragma unroll 4
    for (int it = 0; it < 16; ++it) {
        int kb = it * 32 + j * 4;
        float4 v = *(const float4*)(xr + kb);
#pragma unroll
        for (int c = 0; c < 8; ++c) {
            const float* wt = &sWT[c * 512 + kb];
            acc[c] += v.x * wt[0] + v.y * wt[1] + v.z * wt[2] + v.w * wt[3];
        }
    }
#pragma unroll
    for (int off = 1; off < 8; off <<= 1)
#pragma unroll
        for (int c = 0; c < 8; ++c)
            acc[c] += __shfl_xor(acc[c], off);
    float outv = acc[0];
#pragma unroll
    for (int c = 1; c < 8; ++c) if (j == c) outv = acc[c];
    xw[(size_t)row * 8 + j] = outv * dinv[row];
}

// ---------------- gather 1: h1' = relu(dinv*(sum xw1'[src] + xw1'[d]) + b1) * dinv ----------------
// wave-per-node, 64 lanes = 8 edge-slots x 8 features.

__global__ void k_gather1(const float* __restrict__ xw, const int* __restrict__ csr,
                          const int* __restrict__ row_start, const float* __restrict__ dinv,
                          const float* __restrict__ b, float* __restrict__ out, int n) {
    int wid = (blockIdx.x * blockDim.x + threadIdx.x) >> 6;
    int lane = threadIdx.x & 63;
    if (wid >= n) return;
    int e = lane >> 3, c = lane & 7;
    int k0 = row_start[wid], k1 = row_start[wid + 1];
    float acc = 0.f;
    for (int k = k0 + e; k < k1; k += 8)
        acc += xw[(size_t)csr[k] * 8 + c];
    if (e == 0) acc += xw[(size_t)wid * 8 + c];
#pragma unroll
    for (int off = 8; off < 64; off <<= 1) acc += __shfl_xor(acc, off);
    if (lane < 8) {
        float di = dinv[wid];
        out[(size_t)wid * 8 + c] = fmaxf(acc * di + b[c], 0.f) * di;
    }
}

// ---------------- gather 2 + fused GEMM: h2' = relu((dinv*sum h1')@W2 + b2) * dinv ----------------

__global__ void k_gather2(const float* __restrict__ h1, const int* __restrict__ csr,
                          const int* __restrict__ row_start, const float* __restrict__ dinv,
                          const float* __restrict__ W2, const float* __restrict__ b2,
                          float* __restrict__ h2, int n) {
    __shared__ float sW[8 * 16];
    __shared__ float sB[16];
    if (threadIdx.x < 128) sW[threadIdx.x] = W2[threadIdx.x];
    if (threadIdx.x < 16) sB[threadIdx.x] = b2[threadIdx.x];
    __syncthreads();
    int wid = (blockIdx.x * blockDim.x + threadIdx.x) >> 6;
    int lane = threadIdx.x & 63;
    if (wid >= n) return;
    int e = lane >> 3, c = lane & 7;
    int k0 = row_start[wid], k1 = row_start[wid + 1];
    float acc = 0.f;
    for (int k = k0 + e; k < k1; k += 8)
        acc += h1[(size_t)csr[k] * 8 + c];
    if (e == 0) acc += h1[(size_t)wid * 8 + c];
#pragma unroll
    for (int off = 8; off < 64; off <<= 1) acc += __shfl_xor(acc, off);
    float di = dinv[wid];
    acc *= di;                      // S2[c] in every lane of c-group
    float s2[8];
#pragma unroll
    for (int k = 0; k < 8; ++k) s2[k] = __shfl(acc, k);
    if (lane < 16) {
        float a = sB[lane];
#pragma unroll
        for (int k = 0; k < 8; ++k) a += s2[k] * sW[k * 16 + lane];
        h2[(size_t)wid * 16 + lane] = fmaxf(a, 0.f) * di;
    }
}

// ---------------- gather 3 + fused head: pi/pj from dinv*(sum h2'[src] + h2'[d]) ----------------
// 64 lanes = 4 edge-slots x 16 features.

__global__ void k_gather3(const float* __restrict__ h2, const int* __restrict__ csr,
                          const int* __restrict__ row_start, const float* __restrict__ dinv,
                          const float* __restrict__ v, const float* __restrict__ ch,
                          float* __restrict__ pi, float* __restrict__ pj, int n) {
    int wid = (blockIdx.x * blockDim.x + threadIdx.x) >> 6;
    int lane = threadIdx.x & 63;
    if (wid >= n) return;
    int e = lane >> 4, c = lane & 15;
    int k0 = row_start[wid], k1 = row_start[wid + 1];
    float acc = 0.f;
    for (int k = k0 + e; k < k1; k += 4)
        acc += h2[(size_t)csr[k] * 16 + c];
    if (e == 0) acc += h2[(size_t)wid * 16 + c];
#pragma unroll
    for (int off = 16; off < 64; off <<= 1) acc += __shfl_xor(acc, off);
    float t = acc * v[c];
    float u = acc * v[16 + c];
#pragma unroll
    for (int off = 1; off < 16; off <<= 1) {
        t += __shfl_xor(t, off);
        u += __shfl_xor(u, off);
    }
    if (lane == 0) {
        float di = dinv[wid];
        pi[wid] = t * di + ch[0];
        pj[wid] = u * di + ch[1];
    }
}

// ---------------- head prep: fold W3/b3/Wfc into per-node 16-dot ----------------

__global__ void k_prep_head(const float* __restrict__ W3, const float* __restrict__ b3,
                            const float* __restrict__ Wfc, float* __restrict__ v,
                            float* __restrict__ c) {
    int t = threadIdx.x;
    if (t < 32) {
        int j = t & 15;
        const float* wf = Wfc + (t < 16 ? 0 : 32);
        float a = 0.f;
        for (int k = 0; k < 32; ++k) a += W3[j * 32 + k] * wf[k];
        v[t] = a;
    } else if (t < 34) {
        const float* wf = Wfc + (t == 32 ? 0 : 32);
        float a = 0.f;
        for (int k = 0; k < 32; ++k) a += b3[k] * wf[k];
        c[t - 32] = a;
    }
}

// ---------------- sample head ----------------

__global__ void k_samples_fast(const int2* __restrict__ samples, const float* __restrict__ pi,
                               const float* __restrict__ pj, const float* __restrict__ bfc,
                               float* __restrict__ out, int S) {
    int i = blockIdx.x * blockDim.x + threadIdx.x;
    if (i >= S) return;
    int2 s = samples[i];
    float z = pi[s.x] + pj[s.y] + bfc[0];
    out[i] = 1.0f / (1.0f + __expf(-z));
}

// ---------------- launch ----------------

extern "C" void kernel_launch(void* const* d_in, const int* in_sizes, int n_in,
                              void* d_out, int out_size, void* d_ws, size_t ws_size,
                              hipStream_t stream) {
    const float* x   = (const float*)d_in[0];
    const int*   ei  = (const int*)d_in[1];
    const int*   smp = (const int*)d_in[2];
    const float* W1  = (const float*)d_in[3];
    const float* b1  = (const float*)d_in[4];
    const float* W2  = (const float*)d_in[5];
    const float* b2  = (const float*)d_in[6];
    const float* W3  = (const float*)d_in[7];
    const float* b3  = (const float*)d_in[8];
    const float* Wfc = (const float*)d_in[9];
    const float* bfc = (const float*)d_in[10];
    float* out = (float*)d_out;

    const int E = in_sizes[1] / 2;
    const int S = in_sizes[2] / 2;
    const int N = N_NODES;
    const int* src = ei;
    const int* dst = ei + E;

    char* w = (char*)d_ws;
    size_t off = 0;
    auto alloc = [&](size_t bytes) {
        char* p = w + off;
        off += (bytes + 255) & ~(size_t)255;
        return p;
    };
    int*   row_start = (int*)alloc((N + 1) * 4);
    float* dinv      = (float*)alloc(N * 4);
    int*   csr       = (int*)alloc((size_t)E * 4);
    int*   btot      = (int*)alloc(NBKT * 4);
    int*   bbase     = (int*)alloc((NBKT + 1) * 4);

    // layer buffers; tmp/hist/offs (partition scratch, ~17MB) overlay this
    // region — all dead before the first layer kernel runs.
    size_t off_layers = off;
    float* xw1       = (float*)alloc((size_t)N * 8 * 4);
    float* h1        = (float*)alloc((size_t)N * 8 * 4);
    float* h2        = (float*)alloc((size_t)N * 16 * 4);
    float* vhead     = (float*)alloc(32 * 4);
    float* chead     = (float*)alloc(2 * 4);
    float* pi        = (float*)alloc(N * 4);
    float* pj        = (float*)alloc(N * 4);

    size_t tmp_off  = off_layers;
    size_t hist_off = tmp_off + (((size_t)E * 4 + 255) & ~(size_t)255);
    size_t offs_off = hist_off + (((size_t)NBLK * NBKT * 4 + 255) & ~(size_t)255);
    int* tmp  = (int*)(w + tmp_off);
    int* hist = (int*)(w + hist_off);
    int* offs = (int*)(w + offs_off);
    size_t scratch_end = offs_off + (size_t)NBLK * NBKT * 4;
    if (scratch_end > off) off = (scratch_end + 255) & ~(size_t)255;

    dim3 B(256);
    const int GN = (N * 64 + 255) / 256;   // wave-per-node grids

    // CSR build: zero global atomics, zero memsets, single tmp re-read.
    k_hist<<<dim3(NBLK), dim3(TPB_P), 0, stream>>>(dst, hist, E);
    k_offs<<<dim3(NBKT * 64 / 256), B, 0, stream>>>(hist, offs, btot);
    k_bktscan<<<dim3(1), B, 0, stream>>>(btot, bbase);
    k_place<<<dim3(NBLK), dim3(TPB_P), 0, stream>>>(src, dst, offs, bbase, tmp, E);
    k_finalize<<<dim3(NBKT), B, 0, stream>>>(tmp, bbase, row_start, dinv, csr, N);

    // layer 1: xw1' = (x@W1)*dinv ; h1' = relu(dinv*agg + b1)*dinv
    k_gemm1<<<dim3(((N + 7) / 8 * 64 + 255) / 256), B, 0, stream>>>(x, W1, dinv, xw1, N);
    k_gather1<<<dim3(GN), B, 0, stream>>>(xw1, csr, row_start, dinv, b1, h1, N);

    // layer 2 (linearity): h2' = relu((dinv*agg)@W2 + b2)*dinv, GEMM fused in-wave
    k_gather2<<<dim3(GN), B, 0, stream>>>(h1, csr, row_start, dinv, W2, b2, h2, N);

    // layer 3 (linearity) + head fold: pi/pj directly from dinv*agg16(h2')
    k_prep_head<<<dim3(1), dim3(64), 0, stream>>>(W3, b3, Wfc, vhead, chead);
    k_gather3<<<dim3(GN), B, 0, stream>>>(h2, csr, row_start, dinv, vhead, chead, pi, pj, N);

    // per-sample sigmoid
    k_samples_fast<<<dim3((S + 255) / 256), B, 0, stream>>>((const int2*)smp, pi, pj, bfc, out, S);
}